// Round 3
// baseline (2676.915 us; speedup 1.0000x reference)
//
#include <hip/hip_runtime.h>

#define EPS 1e-7f

constexpr int B = 8, C = 64, H = 256, W = 448;
constexpr int N = H * W;          // 114688
constexpr int P = B * N;          // 917504

constexpr int TH = 32, TW = 64;   // exclusive output tile
constexpr int R  = 6;             // halo radius (covers |flow| <= 5)
constexpr int WH = TH + 2 * R;    // 44 window rows
constexpr int WW = TW + 2 * R;    // 76 window cols (compile-time -> cheap div)
constexpr int NSRC = WH * WW;     // 3344
constexpr int NT = 512;
constexpr int ITERS = (NSRC + NT - 1) / NT;  // 7 (fully unrolled; static reg indexing)
constexpr int PS = TW + 4;        // 68: float4-aligned, breaks bank aliasing
constexpr int PLANE = TH * PS;    // 2176 words
constexpr int NCH = 8;            // channels per LDS pass
constexpr int TILES_X = W / TW, TILES_Y = H / TH;   // 7, 8
constexpr int TILES = B * TILES_X * TILES_Y;        // 448
constexpr float FMAX = (float)(R - 1);              // 5.0

__global__ __launch_bounds__(NT) void softsplat_gather(
    const float* __restrict__ x,
    const float* __restrict__ flow,
    const float* __restrict__ metric,
    float* __restrict__ out,      // [B, C, N] numerator
    float* __restrict__ den)      // [B, N]    denominator
{
    __shared__ float acc[NCH * PLANE];   // 69,632 B -> 2 blocks/CU

    const int tile = blockIdx.x;
    const int half = blockIdx.y;         // 0: ch 0-31 + den, 1: ch 32-63
    const int b  = tile / (TILES_X * TILES_Y);
    const int tp = tile % (TILES_X * TILES_Y);
    const int r0 = (tp / TILES_X) * TH;
    const int c0 = (tp % TILES_X) * TW;
    const int tid = threadIdx.x;

    const float* fx_p = flow + (size_t)(b * 2 + 0) * N;
    const float* fy_p = flow + (size_t)(b * 2 + 1) * N;
    const float* m_p  = metric + (size_t)b * N;

    // ---- geometry phase: once per block, all in registers (static indices) ----
    float w0[ITERS], w1[ITERS], w2[ITERS], w3[ITERS];
    int   ia[ITERS], ib[ITERS];          // packed (i00 | i10<<16), (i01 | i11<<16)
    int   spv[ITERS];

    #pragma unroll
    for (int i = 0; i < ITERS; ++i) {
        const int s  = tid + i * NT;
        const int sh = r0 - R + s / WW;
        const int sw = c0 - R + s % WW;
        bool vsrc = (s < NSRC) & (sh >= 0) & (sh < H) & (sw >= 0) & (sw < W);
        const int sp = vsrc ? sh * W + sw : 0;
        spv[i] = sp;
        const float fdx = fx_p[sp], fdy = fy_p[sp];
        vsrc = vsrc & (fabsf(fdx) <= FMAX) & (fabsf(fdy) <= FMAX);  // outlier pass covers rest

        const float tx = (float)sw + fdx, ty = (float)sh + fdy;
        const float x0f = floorf(tx), y0f = floorf(ty);
        const int lx0 = (int)x0f - c0, ly0 = (int)y0f - r0;
        const int lx1 = lx0 + 1,       ly1 = ly0 + 1;
        const bool vx0 = (unsigned)lx0 < (unsigned)TW;
        const bool vx1 = (unsigned)lx1 < (unsigned)TW;
        const bool vy0 = (unsigned)ly0 < (unsigned)TH;
        const bool vy1 = (unsigned)ly1 < (unsigned)TH;

        const float m  = vsrc ? __expf(m_p[sp]) : 0.f;
        const float fx = tx - x0f, fy = ty - y0f;
        w0[i] = (vx0 && vy0) ? (1.f - fx) * (1.f - fy) * m : 0.f;
        w1[i] = (vx1 && vy0) ? fx * (1.f - fy) * m : 0.f;
        w2[i] = (vx0 && vy1) ? (1.f - fx) * fy * m : 0.f;
        w3[i] = (vx1 && vy1) ? fx * fy * m : 0.f;

        // clamp per-corner into the plane; weight 0 makes the add a no-op
        const int cx0 = min(max(lx0, 0), TW - 1), cx1 = min(max(lx1, 0), TW - 1);
        const int cy0 = min(max(ly0, 0), TH - 1), cy1 = min(max(ly1, 0), TH - 1);
        ia[i] = (cy0 * PS + cx0) | ((cy0 * PS + cx1) << 16);
        ib[i] = (cy1 * PS + cx0) | ((cy1 * PS + cx1) << 16);
    }

    // ---- channel passes: 4 x 8 channels, branch-free load+atomic stream ----
    #pragma unroll 1
    for (int cg = 0; cg < 4; ++cg) {
        __syncthreads();   // previous pass's writeback reads done
        for (int k = tid; k < NCH * PLANE; k += NT) acc[k] = 0.f;
        __syncthreads();

        const float* xb = x + ((size_t)b * C + half * 32 + cg * NCH) * N;
        #pragma unroll
        for (int i = 0; i < ITERS; ++i) {
            const int i00 = ia[i] & 0xffff, i10 = ia[i] >> 16;
            const int i01 = ib[i] & 0xffff, i11 = ib[i] >> 16;
            #pragma unroll
            for (int c = 0; c < NCH; ++c) {
                const float v = xb[(size_t)c * N + spv[i]];
                float* pl = acc + c * PLANE;
                atomicAdd(pl + i00, v * w0[i]);
                atomicAdd(pl + i10, v * w1[i]);
                atomicAdd(pl + i01, v * w2[i]);
                atomicAdd(pl + i11, v * w3[i]);
            }
        }
        __syncthreads();

        // coalesced float4 writeback of the exclusive tile
        for (int k = tid; k < NCH * TH * (TW / 4); k += NT) {
            const int c   = k / (TH * (TW / 4));
            const int rem = k % (TH * (TW / 4));
            const int yy  = rem / (TW / 4), xg = rem % (TW / 4);
            const float* src = acc + c * PLANE + yy * PS + xg * 4;
            *reinterpret_cast<float4*>(
                out + ((size_t)(b * C + half * 32 + cg * NCH + c) * H + r0 + yy) * W + c0 + xg * 4) =
                make_float4(src[0], src[1], src[2], src[3]);
        }
    }

    // ---- denominator: half-0 blocks only, pure register adds ----
    if (half == 0) {
        __syncthreads();
        for (int k = tid; k < PLANE; k += NT) acc[k] = 0.f;
        __syncthreads();
        #pragma unroll
        for (int i = 0; i < ITERS; ++i) {
            const int i00 = ia[i] & 0xffff, i10 = ia[i] >> 16;
            const int i01 = ib[i] & 0xffff, i11 = ib[i] >> 16;
            atomicAdd(acc + i00, w0[i]);
            atomicAdd(acc + i10, w1[i]);
            atomicAdd(acc + i01, w2[i]);
            atomicAdd(acc + i11, w3[i]);
        }
        __syncthreads();
        float* db = den + (size_t)b * N;
        for (int k = tid; k < TH * (TW / 4); k += NT) {
            const int yy = k / (TW / 4), xg = k % (TW / 4);
            const float* src = acc + yy * PS + xg * 4;
            *reinterpret_cast<float4*>(db + (size_t)(r0 + yy) * W + c0 + xg * 4) =
                make_float4(src[0], src[1], src[2], src[3]);
        }
    }
}

// Exact complement of the gather's outlier-skip predicate; global atomics.
__global__ __launch_bounds__(256) void softsplat_outlier(
    const float* __restrict__ x,
    const float* __restrict__ flow,
    const float* __restrict__ metric,
    float* __restrict__ out,
    float* __restrict__ den)
{
    int t = blockIdx.x * blockDim.x + threadIdx.x;
    if (t >= P) return;
    int b = t / N;
    int p = t - b * N;
    float fdx = flow[(size_t)(b * 2 + 0) * N + p];
    float fdy = flow[(size_t)(b * 2 + 1) * N + p];
    if (fabsf(fdx) <= FMAX && fabsf(fdy) <= FMAX) return;

    int h = p / W, w = p - h * W;
    float m = __expf(metric[(size_t)b * N + p]);
    float tx = (float)w + fdx, ty = (float)h + fdy;
    float x0f = floorf(tx), y0f = floorf(ty);
    int x0 = (int)x0f, y0 = (int)y0f, x1 = x0 + 1, y1 = y0 + 1;
    float fx = tx - x0f, fy = ty - y0f;
    float w00 = (1.f - fx) * (1.f - fy), w10 = fx * (1.f - fy);
    float w01 = (1.f - fx) * fy,         w11 = fx * fy;
    bool vx0 = (x0 >= 0) && (x0 < W), vx1 = (x1 >= 0) && (x1 < W);
    bool vy0 = (y0 >= 0) && (y0 < H), vy1 = (y1 >= 0) && (y1 < H);
    int cx0 = min(max(x0, 0), W - 1), cx1 = min(max(x1, 0), W - 1);
    int cy0 = min(max(y0, 0), H - 1), cy1 = min(max(y1, 0), H - 1);
    int i00 = cy0 * W + cx0, i10 = cy0 * W + cx1;
    int i01 = cy1 * W + cx0, i11 = cy1 * W + cx1;
    w00 = (vx0 && vy0) ? w00 * m : 0.f;
    w10 = (vx1 && vy0) ? w10 * m : 0.f;
    w01 = (vx0 && vy1) ? w01 * m : 0.f;
    w11 = (vx1 && vy1) ? w11 * m : 0.f;

    float* denb = den + (size_t)b * N;
    if (w00 != 0.f) atomicAdd(denb + i00, w00);
    if (w10 != 0.f) atomicAdd(denb + i10, w10);
    if (w01 != 0.f) atomicAdd(denb + i01, w01);
    if (w11 != 0.f) atomicAdd(denb + i11, w11);

    const float* xb = x + (size_t)b * C * N + p;
    float* ob = out + (size_t)b * C * N;
    for (int c = 0; c < C; ++c) {
        float v = xb[(size_t)c * N];
        float* o = ob + (size_t)c * N;
        if (w00 != 0.f) atomicAdd(o + i00, v * w00);
        if (w10 != 0.f) atomicAdd(o + i10, v * w10);
        if (w01 != 0.f) atomicAdd(o + i01, v * w01);
        if (w11 != 0.f) atomicAdd(o + i11, v * w11);
    }
}

__global__ __launch_bounds__(256) void softsplat_norm(
    float* __restrict__ out, const float* __restrict__ den)
{
    size_t t = (size_t)blockIdx.x * blockDim.x + threadIdx.x;  // one float4
    size_t e = t * 4;
    if (e >= (size_t)B * C * N) return;
    size_t b = e / ((size_t)C * N);
    size_t p = (e - b * (size_t)C * N) % N;   // N % 4 == 0

    float4 o = *reinterpret_cast<float4*>(out + e);
    const float4 d = *reinterpret_cast<const float4*>(den + b * N + p);
    o.x = o.x / (d.x + EPS);
    o.y = o.y / (d.y + EPS);
    o.z = o.z / (d.z + EPS);
    o.w = o.w / (d.w + EPS);
    *reinterpret_cast<float4*>(out + e) = o;
}

extern "C" void kernel_launch(void* const* d_in, const int* in_sizes, int n_in,
                              void* d_out, int out_size, void* d_ws, size_t ws_size,
                              hipStream_t stream) {
    const float* x      = (const float*)d_in[0];
    const float* flow   = (const float*)d_in[1];
    const float* metric = (const float*)d_in[2];
    float* out = (float*)d_out;
    float* den = (float*)d_ws;

    dim3 grid(TILES, 2);   // 448 tiles x 2 channel-halves (half 0 also does den)
    softsplat_gather<<<grid, NT, 0, stream>>>(x, flow, metric, out, den);

    softsplat_outlier<<<(P + 255) / 256, 256, 0, stream>>>(x, flow, metric, out, den);

    size_t nvec4 = (size_t)B * C * N / 4;
    softsplat_norm<<<(int)((nvec4 + 255) / 256), 256, 0, stream>>>(out, den);
}

// Round 4
// 2232.596 us; speedup vs baseline: 1.1990x; 1.1990x over previous
//
#include <hip/hip_runtime.h>

#define EPS 1e-7f

constexpr int B = 8, C = 64, H = 256, W = 448;
constexpr int N = H * W;          // 114688
constexpr int P = B * N;          // 917504

constexpr int TH = 32, TW = 64;   // exclusive output tile
constexpr int R  = 6;             // halo radius (covers |flow| <= 5)
constexpr int WH = TH + 2 * R;    // 44 window rows
constexpr int WW = TW + 2 * R;    // 76 window cols (compile-time divisor)
constexpr int NSRC = WH * WW;     // 3344
constexpr int NT = 1024;          // 16 waves/block, 2 blocks/CU -> 32 waves/CU
constexpr int PS = TW + 4;        // 68: float4-aligned pad
constexpr int PLANE = TH * PS;    // 2176 words
constexpr int NCH = 8;            // channels per chunk block
constexpr int TILES_X = W / TW, TILES_Y = H / TH;   // 7, 8
constexpr int TILES = B * TILES_X * TILES_Y;        // 448
constexpr float FMAX = (float)(R - 1);              // 5.0

__global__ __launch_bounds__(NT, 8) void softsplat_gather(
    const float* __restrict__ x,
    const float* __restrict__ flow,
    const float* __restrict__ metric,
    float* __restrict__ out,      // [B, C, N] numerator
    float* __restrict__ den)      // [B, N]    denominator
{
    __shared__ float acc[NCH * PLANE];   // 69,632 B -> 2 blocks/CU

    const int tile  = blockIdx.x;
    const int chunk = blockIdx.y;        // 0..7 = channel chunks, 8 = denominator
    const int b  = tile / (TILES_X * TILES_Y);
    const int tp = tile % (TILES_X * TILES_Y);
    const int r0 = (tp / TILES_X) * TH;
    const int c0 = (tp % TILES_X) * TW;
    const int tid = threadIdx.x;
    const bool isden = (chunk == NCH);

    const int nwords = isden ? PLANE : NCH * PLANE;
    for (int i = tid; i < nwords; i += NT) acc[i] = 0.f;
    __syncthreads();

    const float* fx_p = flow + (size_t)(b * 2 + 0) * N;
    const float* fy_p = flow + (size_t)(b * 2 + 1) * N;
    const float* m_p  = metric + (size_t)b * N;
    const float* xb   = x + ((size_t)b * C + (isden ? 0 : chunk * NCH)) * N;

    // branch-free main loop: geometry inline, weights zeroed for any invalid
    // condition, indices clamped into the LDS plane, atomics unconditional.
    for (int s = tid; s < NSRC; s += NT) {
        const int wy = s / WW;            // compile-time divisor -> magic mul
        const int wx = s - wy * WW;
        const int sh = r0 - R + wy;
        const int sw = c0 - R + wx;
        const bool vsrc = (sh >= 0) & (sh < H) & (sw >= 0) & (sw < W);
        const int sp = vsrc ? sh * W + sw : 0;

        const float fdx = fx_p[sp], fdy = fy_p[sp];
        // |flow|>FMAX handled exactly by the outlier fixup pass
        const bool ok = vsrc & (fabsf(fdx) <= FMAX) & (fabsf(fdy) <= FMAX);

        const float tx = (float)sw + fdx, ty = (float)sh + fdy;
        const float x0f = floorf(tx), y0f = floorf(ty);
        const int lx0 = (int)x0f - c0, ly0 = (int)y0f - r0;
        const int lx1 = lx0 + 1,       ly1 = ly0 + 1;
        const bool vx0 = (unsigned)lx0 < (unsigned)TW;
        const bool vx1 = (unsigned)lx1 < (unsigned)TW;
        const bool vy0 = (unsigned)ly0 < (unsigned)TH;
        const bool vy1 = (unsigned)ly1 < (unsigned)TH;

        const float m  = ok ? __expf(m_p[sp]) : 0.f;
        const float fxf = tx - x0f, fyf = ty - y0f;
        const float w0 = (vx0 && vy0) ? (1.f - fxf) * (1.f - fyf) * m : 0.f;
        const float w1 = (vx1 && vy0) ? fxf * (1.f - fyf) * m : 0.f;
        const float w2 = (vx0 && vy1) ? (1.f - fxf) * fyf * m : 0.f;
        const float w3 = (vx1 && vy1) ? fxf * fyf * m : 0.f;

        const int cx0 = min(max(lx0, 0), TW - 1), cx1 = min(max(lx1, 0), TW - 1);
        const int cy0 = min(max(ly0, 0), TH - 1), cy1 = min(max(ly1, 0), TH - 1);
        const int i00 = cy0 * PS + cx0, i10 = cy0 * PS + cx1;
        const int i01 = cy1 * PS + cx0, i11 = cy1 * PS + cx1;

        if (isden) {   // block-uniform branch
            atomicAdd(acc + i00, w0);
            atomicAdd(acc + i10, w1);
            atomicAdd(acc + i01, w2);
            atomicAdd(acc + i11, w3);
        } else {
            #pragma unroll
            for (int c = 0; c < NCH; ++c) {
                const float v = xb[(size_t)c * N + sp];
                float* pl = acc + c * PLANE;   // c*PLANE*4 fits ds offset imm
                atomicAdd(pl + i00, v * w0);
                atomicAdd(pl + i10, v * w1);
                atomicAdd(pl + i01, v * w2);
                atomicAdd(pl + i11, v * w3);
            }
        }
    }
    __syncthreads();

    // non-atomic coalesced float4 writeback of the exclusive tile
    if (isden) {
        float* db = den + (size_t)b * N;
        for (int k = tid; k < TH * (TW / 4); k += NT) {
            const int yy = k / (TW / 4), xg = k % (TW / 4);
            const float* src = acc + yy * PS + xg * 4;
            *reinterpret_cast<float4*>(db + (size_t)(r0 + yy) * W + c0 + xg * 4) =
                make_float4(src[0], src[1], src[2], src[3]);
        }
    } else {
        for (int k = tid; k < NCH * TH * (TW / 4); k += NT) {
            const int c   = k / (TH * (TW / 4));
            const int rem = k % (TH * (TW / 4));
            const int yy  = rem / (TW / 4), xg = rem % (TW / 4);
            const float* src = acc + c * PLANE + yy * PS + xg * 4;
            *reinterpret_cast<float4*>(
                out + ((size_t)(b * C + chunk * NCH + c) * H + r0 + yy) * W + c0 + xg * 4) =
                make_float4(src[0], src[1], src[2], src[3]);
        }
    }
}

// Exact complement of the gather's skip predicate; global atomics on top.
__global__ __launch_bounds__(256) void softsplat_outlier(
    const float* __restrict__ x,
    const float* __restrict__ flow,
    const float* __restrict__ metric,
    float* __restrict__ out,
    float* __restrict__ den)
{
    int t = blockIdx.x * blockDim.x + threadIdx.x;
    if (t >= P) return;
    int b = t / N;
    int p = t - b * N;
    float fdx = flow[(size_t)(b * 2 + 0) * N + p];
    float fdy = flow[(size_t)(b * 2 + 1) * N + p];
    if (fabsf(fdx) <= FMAX && fabsf(fdy) <= FMAX) return;

    int h = p / W, w = p - h * W;
    float m = __expf(metric[(size_t)b * N + p]);
    float tx = (float)w + fdx, ty = (float)h + fdy;
    float x0f = floorf(tx), y0f = floorf(ty);
    int x0 = (int)x0f, y0 = (int)y0f, x1 = x0 + 1, y1 = y0 + 1;
    float fx = tx - x0f, fy = ty - y0f;
    float w00 = (1.f - fx) * (1.f - fy), w10 = fx * (1.f - fy);
    float w01 = (1.f - fx) * fy,         w11 = fx * fy;
    bool vx0 = (x0 >= 0) && (x0 < W), vx1 = (x1 >= 0) && (x1 < W);
    bool vy0 = (y0 >= 0) && (y0 < H), vy1 = (y1 >= 0) && (y1 < H);
    int cx0 = min(max(x0, 0), W - 1), cx1 = min(max(x1, 0), W - 1);
    int cy0 = min(max(y0, 0), H - 1), cy1 = min(max(y1, 0), H - 1);
    int i00 = cy0 * W + cx0, i10 = cy0 * W + cx1;
    int i01 = cy1 * W + cx0, i11 = cy1 * W + cx1;
    w00 = (vx0 && vy0) ? w00 * m : 0.f;
    w10 = (vx1 && vy0) ? w10 * m : 0.f;
    w01 = (vx0 && vy1) ? w01 * m : 0.f;
    w11 = (vx1 && vy1) ? w11 * m : 0.f;

    float* denb = den + (size_t)b * N;
    if (w00 != 0.f) atomicAdd(denb + i00, w00);
    if (w10 != 0.f) atomicAdd(denb + i10, w10);
    if (w01 != 0.f) atomicAdd(denb + i01, w01);
    if (w11 != 0.f) atomicAdd(denb + i11, w11);

    const float* xb = x + (size_t)b * C * N + p;
    float* ob = out + (size_t)b * C * N;
    for (int c = 0; c < C; ++c) {
        float v = xb[(size_t)c * N];
        float* o = ob + (size_t)c * N;
        if (w00 != 0.f) atomicAdd(o + i00, v * w00);
        if (w10 != 0.f) atomicAdd(o + i10, v * w10);
        if (w01 != 0.f) atomicAdd(o + i01, v * w01);
        if (w11 != 0.f) atomicAdd(o + i11, v * w11);
    }
}

__global__ __launch_bounds__(256) void softsplat_norm(
    float* __restrict__ out, const float* __restrict__ den)
{
    size_t t = (size_t)blockIdx.x * blockDim.x + threadIdx.x;  // one float4
    size_t e = t * 4;
    if (e >= (size_t)B * C * N) return;
    size_t b = e / ((size_t)C * N);
    size_t p = (e - b * (size_t)C * N) % N;   // N % 4 == 0

    float4 o = *reinterpret_cast<float4*>(out + e);
    const float4 d = *reinterpret_cast<const float4*>(den + b * N + p);
    o.x = o.x / (d.x + EPS);
    o.y = o.y / (d.y + EPS);
    o.z = o.z / (d.z + EPS);
    o.w = o.w / (d.w + EPS);
    *reinterpret_cast<float4*>(out + e) = o;
}

extern "C" void kernel_launch(void* const* d_in, const int* in_sizes, int n_in,
                              void* d_out, int out_size, void* d_ws, size_t ws_size,
                              hipStream_t stream) {
    const float* x      = (const float*)d_in[0];
    const float* flow   = (const float*)d_in[1];
    const float* metric = (const float*)d_in[2];
    float* out = (float*)d_out;
    float* den = (float*)d_ws;

    dim3 grid(TILES, NCH + 1);   // 448 tiles x (8 channel chunks + 1 den)
    softsplat_gather<<<grid, NT, 0, stream>>>(x, flow, metric, out, den);

    softsplat_outlier<<<(P + 255) / 256, 256, 0, stream>>>(x, flow, metric, out, den);

    size_t nvec4 = (size_t)B * C * N / 4;
    softsplat_norm<<<(int)((nvec4 + 255) / 256), 256, 0, stream>>>(out, den);
}